// Round 10
// baseline (280.286 us; speedup 1.0000x reference)
//
#include <hip/hip_runtime.h>
#include <hip/hip_bf16.h>

// Problem constants
#define NB    16          // batch
#define SP    1024        // H*W spatial
#define NC    512         // channels
#define NG    32          // groups
#define MTOT  (NB*SP)     // 16384
#define EPSV  1e-3f
#define SCALE 0.04419417382415922f  // 512^-0.5

using f32x4   = __attribute__((ext_vector_type(4))) float;
using short8  = __attribute__((ext_vector_type(8))) short;
using short4v = __attribute__((ext_vector_type(4))) short;
using bf16x8v = __attribute__((ext_vector_type(8))) __bf16;

__device__ __forceinline__ unsigned short f2bf(float f) {
  union { float f; unsigned int u; } x; x.f = f;
  unsigned int u = x.u;
  unsigned int r = (u + 0x7FFFu + ((u >> 16) & 1u)) >> 16;  // RNE
  return (unsigned short)r;
}
__device__ __forceinline__ float bf2f(unsigned short b) {
  union { unsigned int u; float f; } x; x.u = ((unsigned int)b) << 16;
  return x.f;
}

// async 16B global->LDS (gfx950). LDS dest = wave-uniform base + lane*16.
#define GLOAD_LDS16(g, l)                                                     \
  __builtin_amdgcn_global_load_lds(                                           \
      (const __attribute__((address_space(1))) void*)(g),                     \
      (__attribute__((address_space(3))) void*)(l), 16, 0, 0)

// ---------------------------------------------------------------- GN stats
__global__ __launch_bounds__(256) void gn_stats_k(const float* __restrict__ x,
                                                  float2* __restrict__ stats) {
  int bg = blockIdx.x;            // b*32+g
  int b = bg >> 5, g = bg & 31;
  int tid = threadIdx.x;
  int c = tid & 15, s0 = tid >> 4;
  const float* base = x + (long)b * SP * NC + g * 16 + c;
  float s = 0.f, ss = 0.f;
  for (int sp = s0; sp < SP; sp += 16) {
    float v = base[(long)sp * NC];
    s += v; ss += v * v;
  }
  for (int o = 32; o > 0; o >>= 1) { s += __shfl_xor(s, o); ss += __shfl_xor(ss, o); }
  __shared__ float rs[4], rss[4];
  int lane = tid & 63, wv = tid >> 6;
  if (lane == 0) { rs[wv] = s; rss[wv] = ss; }
  __syncthreads();
  if (tid == 0) {
    float S = rs[0] + rs[1] + rs[2] + rs[3];
    float SS = rss[0] + rss[1] + rss[2] + rss[3];
    float mean = S * (1.f / 16384.f);
    float var  = SS * (1.f / 16384.f) - mean * mean;
    stats[bg] = make_float2(mean, rsqrtf(var + EPSV));
  }
}

// ---------------------------------------------------------------- GN apply -> xn bf16
__global__ __launch_bounds__(256) void gn_apply_k(const float* __restrict__ x,
                                                  const float2* __restrict__ stats,
                                                  const float* __restrict__ gamma,
                                                  const float* __restrict__ beta,
                                                  unsigned short* __restrict__ xn) {
  long t = (long)blockIdx.x * 256 + threadIdx.x;
  long base = t * 8;
  int c = (int)(base & 511);
  int b = (int)(base >> 19);
  float2 st = stats[b * NG + (c >> 4)];
  f32x4 v0 = *reinterpret_cast<const f32x4*>(x + base);
  f32x4 v1 = *reinterpret_cast<const f32x4*>(x + base + 4);
  f32x4 g0 = *reinterpret_cast<const f32x4*>(gamma + c);
  f32x4 g1 = *reinterpret_cast<const f32x4*>(gamma + c + 4);
  f32x4 b0 = *reinterpret_cast<const f32x4*>(beta + c);
  f32x4 b1 = *reinterpret_cast<const f32x4*>(beta + c + 4);
  short8 o;
  #pragma unroll
  for (int q = 0; q < 4; ++q) {
    float sc = st.y * g0[q];
    o[q] = (short)f2bf(v0[q] * sc + (b0[q] - st.x * sc));
  }
  #pragma unroll
  for (int q = 0; q < 4; ++q) {
    float sc = st.y * g1[q];
    o[q + 4] = (short)f2bf(v1[q] * sc + (b1[q] - st.x * sc));
  }
  *reinterpret_cast<short8*>(xn + base) = o;
}

// ---------------------------------------------------------------- weight packing
__global__ __launch_bounds__(256) void pack_wqkv_k(const float* __restrict__ W,
                                                   const float* __restrict__ bq,
                                                   unsigned short* __restrict__ Wp,
                                                   float* __restrict__ bp) {
  int idx = blockIdx.x * 256 + threadIdx.x;     // 786432
  int n = idx >> 9, c = idx & 511;
  int e = n >> 9, a = n & 511;
  Wp[idx] = f2bf(W[((long)c * 512 + a) * 3 + e]);
  if (idx < 1536) {
    int e2 = idx >> 9, a2 = idx & 511;
    bp[idx] = bq[a2 * 3 + e2];
  }
}

__global__ __launch_bounds__(256) void pack_wout_k(const float* __restrict__ W,
                                                   unsigned short* __restrict__ Wp) {
  int idx = blockIdx.x * 256 + threadIdx.x;     // 262144
  int n = idx >> 9, c = idx & 511;
  Wp[idx] = f2bf(W[(long)c * 512 + n]);
}

// ---------------------------------------------------------------- V transpose
__global__ void transpose_v_k(const unsigned short* __restrict__ qkv,
                              unsigned short* __restrict__ vT) {
  __shared__ unsigned short t[32][33];
  int bs = blockIdx.x, bc = blockIdx.y, b = blockIdx.z;
  int tx = threadIdx.x, ty = threadIdx.y;     // 32 x 8
  #pragma unroll
  for (int k = 0; k < 4; ++k) {
    int s = bs * 32 + ty + k * 8, c = bc * 32 + tx;
    t[ty + k * 8][tx] = qkv[((long)b * SP + s) * 1536 + 1024 + c];
  }
  __syncthreads();
  #pragma unroll
  for (int k = 0; k < 4; ++k) {
    int c = bc * 32 + ty + k * 8, s = bs * 32 + tx;
    vT[((long)b * NC + c) * SP + s] = t[tx][ty + k * 8];
  }
}

// ---------------------------------------------------------------- softmax (bf16 in-place)
__global__ __launch_bounds__(256) void softmax_k(unsigned short* __restrict__ S) {
  long row = blockIdx.x;
  unsigned short* r = S + row * 1024;
  int tid = threadIdx.x, lane = tid & 63, wv = tid >> 6;
  short4v raw = *reinterpret_cast<const short4v*>(r + tid * 4);
  float v[4];
  #pragma unroll
  for (int q = 0; q < 4; ++q) v[q] = bf2f((unsigned short)raw[q]);
  float m = fmaxf(fmaxf(v[0], v[1]), fmaxf(v[2], v[3]));
  for (int o = 32; o > 0; o >>= 1) m = fmaxf(m, __shfl_xor(m, o));
  __shared__ float wm[4], ws[4];
  if (lane == 0) wm[wv] = m;
  __syncthreads();
  float rmax = fmaxf(fmaxf(wm[0], wm[1]), fmaxf(wm[2], wm[3]));
  float e[4]; float ssum = 0.f;
  #pragma unroll
  for (int q = 0; q < 4; ++q) { e[q] = __expf(v[q] - rmax); ssum += e[q]; }
  for (int o = 32; o > 0; o >>= 1) ssum += __shfl_xor(ssum, o);
  if (lane == 0) ws[wv] = ssum;
  __syncthreads();
  float inv = 1.f / (ws[0] + ws[1] + ws[2] + ws[3]);
  short4v pv;
  #pragma unroll
  for (int q = 0; q < 4; ++q) pv[q] = (short)f2bf(e[q] * inv);
  *reinterpret_cast<short4v*>(r + tid * 4) = pv;
}

// ---------------------------------------------------------------- pipelined TN GEMM v2
// C[m][n] = sum_k A[m][k]*B'[n][k], bf16. Tile 128x256, BK=32, 8 waves (2M x 4N),
// 4-deep LDS K-tile ring (96KB dynamic), staging 3 tiles ahead (global_load_lds).
// Fragment double-buffer -- per sub-iter s:
//   stage(s+3) ; ds_read tile s+1 into ALT frag set ; MFMA on CUR set ;
//   vmcnt(3) [lands s+2] ; s_barrier.
// The 8 ds_reads issue before the 16 MFMAs and complete under them (separate
// pipes); the ONLY LDS wait is the compiler-inserted lgkmcnt at the next
// sub-iter's first MFMA use. One barrier per K-step.
// Ledger: entering s outstanding={s+2}(3), tiles<=s+1 landed; stage->6;
// vmcnt(3) lands s+2; tail vmcnt(0). WAR: stage hits slot (s-1)&3, reads
// drained >=1 barrier earlier. Every s_barrier is preceded by a "memory"
// asm clobber, so reads cannot be hoisted above it.
// LDS swizzle (verified r8, conflicts=0): slot8' = ((r&1)*4+s)^((r>>1)&7).
// EPI: 0 = bf16 out + fp32 bias, 2 = bf16 out * scale, 3 = fp32 out + bias + residual
template <int EPI>
__global__ __launch_bounds__(512, 2) void gemm8(
    const unsigned short* __restrict__ Ap, long strideA, int lda,
    const unsigned short* __restrict__ Bp, long strideB, int ldb,
    void* __restrict__ Op, long strideO, int ldo,
    const float* __restrict__ bias, const float* __restrict__ residual,
    int K, float scale) {
  constexpr int SLOT = 24576;              // A 8KB + B 16KB per K-tile
  extern __shared__ unsigned char smem[];  // 4 * 24576 = 98304
  const int tid = threadIdx.x;
  const int lane = tid & 63, wv = tid >> 6;
  const int wm2 = wv >> 2, wn4 = wv & 3;

  // bijective XCD swizzle (requires nwg % 8 == 0)
  const int nwg  = gridDim.x * gridDim.y;
  const int flat = blockIdx.y * gridDim.x + blockIdx.x;
  const int w    = (flat & 7) * (nwg >> 3) + (flat >> 3);
  const int bn = (w % gridDim.x) * 256;
  const int bm = (w / gridDim.x) * 128;
  const int z = blockIdx.z;
  const unsigned short* Ag = Ap + (long)z * strideA;
  const unsigned short* Bg = Bp + (long)z * strideB;

  // ---- stage-source offsets (inverse-swizzled global addresses; LDS dest linear)
  long offA;
  { int sid = tid, sr = sid >> 3, sl = (sid & 7) ^ (sr & 7);
    offA = (long)(bm + sr * 2 + (sl >> 2)) * lda + (sl & 3) * 8; }
  long offB0, offB1;
  { int sid = tid, sr = sid >> 3, sl = (sid & 7) ^ (sr & 7);
    offB0 = (long)(bn + sr * 2 + (sl >> 2)) * ldb + (sl & 3) * 8;
    sid = 512 + tid; sr = sid >> 3; sl = (sid & 7) ^ (sr & 7);
    offB1 = (long)(bn + sr * 2 + (sl >> 2)) * ldb + (sl & 3) * 8; }
  const int ldsA_off  = wv * 1024;
  const int ldsB0_off = 8192 + wv * 1024;
  const int ldsB1_off = 16384 + wv * 1024;

  // ---- swizzled LDS read offsets (A frags i=0..3, B frags j=0..3)
  int aoff[4], boff[4];
  #pragma unroll
  for (int i = 0; i < 4; ++i) {
    int r = wm2 * 64 + i * 16 + (lane & 15);
    int sr = r >> 1, sl = ((r & 1) * 4 + (lane >> 4)) ^ (sr & 7);
    aoff[i] = sr * 128 + sl * 16;
  }
  #pragma unroll
  for (int j = 0; j < 4; ++j) {
    int r = wn4 * 64 + j * 16 + (lane & 15);
    int sr = r >> 1, sl = ((r & 1) * 4 + (lane >> 4)) ^ (sr & 7);
    boff[j] = 8192 + sr * 128 + sl * 16;
  }

#define STAGE(tt, sb) do { long kt = (long)(tt) * 32;                 \
    GLOAD_LDS16(Ag + offA + kt,  smem + (sb) + ldsA_off);             \
    GLOAD_LDS16(Bg + offB0 + kt, smem + (sb) + ldsB0_off);            \
    GLOAD_LDS16(Bg + offB1 + kt, smem + (sb) + ldsB1_off); } while (0)

#define READS(av, bv, sa) do {                                        \
    _Pragma("unroll")                                                 \
    for (int i = 0; i < 4; ++i)                                       \
      av[i] = *reinterpret_cast<const short8*>((sa) + aoff[i]);       \
    _Pragma("unroll")                                                 \
    for (int j = 0; j < 4; ++j)                                       \
      bv[j] = *reinterpret_cast<const short8*>((sa) + boff[j]); } while (0)

#define MFMA16(av, bv) do {                                           \
    _Pragma("unroll")                                                 \
    for (int i = 0; i < 4; ++i)                                       \
      _Pragma("unroll")                                               \
      for (int j = 0; j < 4; ++j)                                     \
        acc[i][j] = __builtin_amdgcn_mfma_f32_16x16x32_bf16(          \
            __builtin_bit_cast(bf16x8v, av[i]),                       \
            __builtin_bit_cast(bf16x8v, bv[j]), acc[i][j], 0, 0, 0);  \
    } while (0)

  const int NT = K >> 5;
  // ---- prologue: stage tiles 0,1,2 (9 loads); vmcnt(3) lands 0 and 1.
  #pragma unroll
  for (int t = 0; t < 3; ++t)
    if (t < NT) STAGE(t, t * SLOT);
  asm volatile("s_waitcnt vmcnt(3)" ::: "memory");
  __builtin_amdgcn_s_barrier();
  __builtin_amdgcn_sched_barrier(0);

  short8 a0[4], b0[4], a1[4], b1[4];
  READS(a0, b0, smem);                 // tile 0 -> set0
  f32x4 acc[4][4] = {};

  for (int t = 0; t < NT; t += 2) {
    // ---- even sub-iter: consume tile t (set0); read t+1 -> set1; stage t+3
    if (t + 3 < NT) STAGE(t + 3, ((t + 3) & 3) * SLOT);
    if (t + 1 < NT) { const unsigned char* sa = smem + ((t + 1) & 3) * SLOT; READS(a1, b1, sa); }
    __builtin_amdgcn_sched_barrier(0);   // reads issue before MFMAs
    __builtin_amdgcn_s_setprio(1);
    MFMA16(a0, b0);
    __builtin_amdgcn_s_setprio(0);
    __builtin_amdgcn_sched_barrier(0);
    if (t + 3 < NT) asm volatile("s_waitcnt vmcnt(3)" ::: "memory");
    else            asm volatile("s_waitcnt vmcnt(0)" ::: "memory");
    __builtin_amdgcn_s_barrier();
    __builtin_amdgcn_sched_barrier(0);

    // ---- odd sub-iter: consume tile t+1 (set1); read t+2 -> set0; stage t+4
    if (t + 1 < NT) {
      if (t + 4 < NT) STAGE(t + 4, ((t + 4) & 3) * SLOT);
      if (t + 2 < NT) { const unsigned char* sa = smem + ((t + 2) & 3) * SLOT; READS(a0, b0, sa); }
      __builtin_amdgcn_sched_barrier(0);
      __builtin_amdgcn_s_setprio(1);
      MFMA16(a1, b1);
      __builtin_amdgcn_s_setprio(0);
      __builtin_amdgcn_sched_barrier(0);
      if (t + 4 < NT) asm volatile("s_waitcnt vmcnt(3)" ::: "memory");
      else            asm volatile("s_waitcnt vmcnt(0)" ::: "memory");
      __builtin_amdgcn_s_barrier();
      __builtin_amdgcn_sched_barrier(0);
    }
  }
#undef STAGE
#undef READS
#undef MFMA16

  // ---- epilogue  (C/D map: col=lane&15, row=(lane>>4)*4+reg  [m89])
  const int colb = bn + wn4 * 64 + (lane & 15);
  const int rowb = bm + wm2 * 64 + (lane >> 4) * 4;
  #pragma unroll
  for (int i = 0; i < 4; ++i) {
    #pragma unroll
    for (int r = 0; r < 4; ++r) {
      int rowg = rowb + i * 16 + r;
      #pragma unroll
      for (int j = 0; j < 4; ++j) {
        int colg = colb + j * 16;
        float v = acc[i][j][r];
        if (EPI == 0) {
          v += bias[colg];
          ((unsigned short*)Op)[(long)z * strideO + (long)rowg * ldo + colg] = f2bf(v);
        } else if (EPI == 2) {
          ((unsigned short*)Op)[(long)z * strideO + (long)rowg * ldo + colg] = f2bf(v * scale);
        } else {
          v += bias[colg] + residual[(long)rowg * ldo + colg];
          ((float*)Op)[(long)rowg * ldo + colg] = v;
        }
      }
    }
  }
}

// ---------------------------------------------------------------- launch
extern "C" void kernel_launch(void* const* d_in, const int* in_sizes, int n_in,
                              void* d_out, int out_size, void* d_ws, size_t ws_size,
                              hipStream_t stream) {
  const float* x     = (const float*)d_in[0];
  const float* gamma = (const float*)d_in[1];
  const float* beta  = (const float*)d_in[2];
  const float* Wqkv  = (const float*)d_in[3];
  const float* bqkv  = (const float*)d_in[4];
  const float* Wout  = (const float*)d_in[5];
  const float* bout  = (const float*)d_in[6];
  float* out = (float*)d_out;

  char* ws = (char*)d_ws;
  float2*         stats = (float2*)(ws + 0);                    //   4 KB
  unsigned short* wqkvP = (unsigned short*)(ws + 4096);         // 1.5 MB
  float*          bqP   = (float*)(ws + 1576960);               //   6 KB
  unsigned short* woutT = (unsigned short*)(ws + 1583104);      // 0.5 MB
  unsigned short* qkv   = (unsigned short*)(ws + 2107392);      //  48 MB  [16384][1536] bf16
  unsigned short* vT    = (unsigned short*)(ws + 52439040);     //  16 MB  [16][512][1024] bf16
  unsigned short* Sbuf  = (unsigned short*)(ws + 69216256);     //  32 MB  [16][1024][1024] bf16 (P in-place)
  unsigned short* attn  = (unsigned short*)(ws + 136325120);    //  16 MB  [16384][512] bf16
  unsigned short* xn    = (unsigned short*)(ws + 153102336);    //  16 MB  [16384][512] bf16

  // opt in to 96KB dynamic LDS (host-side, not a stream op - capture-safe)
  (void)hipFuncSetAttribute((const void*)gemm8<0>,
        hipFuncAttributeMaxDynamicSharedMemorySize, 98304);
  (void)hipFuncSetAttribute((const void*)gemm8<2>,
        hipFuncAttributeMaxDynamicSharedMemorySize, 98304);
  (void)hipFuncSetAttribute((const void*)gemm8<3>,
        hipFuncAttributeMaxDynamicSharedMemorySize, 98304);

  gn_stats_k<<<512, 256, 0, stream>>>(x, stats);
  gn_apply_k<<<4096, 256, 0, stream>>>(x, stats, gamma, beta, xn);
  pack_wqkv_k<<<3072, 256, 0, stream>>>(Wqkv, bqkv, wqkvP, bqP);
  pack_wout_k<<<1024, 256, 0, stream>>>(Wout, woutT);

  // QKV projection: xn [16384,512] x wqkvP [1536,512]^T -> qkv bf16 [16384][1536]
  gemm8<0><<<dim3(6, 128, 1), 512, 98304, stream>>>(
      xn, 0L, NC, wqkvP, 0L, NC, qkv, 0L, 1536,
      bqP, nullptr, NC, 1.f);

  transpose_v_k<<<dim3(32, 16, 16), dim3(32, 8), 0, stream>>>(qkv, vT);

  // S = Q K^T * scale (bf16 out, per batch): A=q (cols 0..511), B'=k (cols 512..1023)
  gemm8<2><<<dim3(4, 8, 16), 512, 98304, stream>>>(
      qkv, (long)SP * 1536, 1536, qkv + 512, (long)SP * 1536, 1536,
      Sbuf, (long)SP * SP, SP, nullptr, nullptr, NC, SCALE);

  softmax_k<<<MTOT, 256, 0, stream>>>(Sbuf);

  // attn_out = P V  (per batch): A=P bf16 [1024][1024], B'=vT [512][1024]
  gemm8<2><<<dim3(2, 8, 16), 512, 98304, stream>>>(
      Sbuf, (long)SP * SP, SP, vT, (long)NC * SP, SP,
      attn, (long)SP * NC, NC, nullptr, nullptr, SP, 1.f);

  // out = attn_out W_out + b_out + inputs
  gemm8<3><<<dim3(2, 128, 1), 512, 98304, stream>>>(
      attn, 0L, NC, woutT, 0L, NC, out, 0L, NC,
      bout, x, NC, 1.f);
}

// Round 11
// 273.023 us; speedup vs baseline: 1.0266x; 1.0266x over previous
//
#include <hip/hip_runtime.h>
#include <hip/hip_bf16.h>

// Problem constants
#define NB    16          // batch
#define SP    1024        // H*W spatial
#define NC    512         // channels
#define NG    32          // groups
#define MTOT  (NB*SP)     // 16384
#define EPSV  1e-3f
#define SCALE 0.04419417382415922f  // 512^-0.5

using f32x4   = __attribute__((ext_vector_type(4))) float;
using short8  = __attribute__((ext_vector_type(8))) short;
using short4v = __attribute__((ext_vector_type(4))) short;
using bf16x8v = __attribute__((ext_vector_type(8))) __bf16;

__device__ __forceinline__ unsigned short f2bf(float f) {
  union { float f; unsigned int u; } x; x.f = f;
  unsigned int u = x.u;
  unsigned int r = (u + 0x7FFFu + ((u >> 16) & 1u)) >> 16;  // RNE
  return (unsigned short)r;
}
__device__ __forceinline__ float bf2f(unsigned short b) {
  union { unsigned int u; float f; } x; x.u = ((unsigned int)b) << 16;
  return x.f;
}

// async 16B global->LDS (gfx950). LDS dest = wave-uniform base + lane*16.
#define GLOAD_LDS16(g, l)                                                     \
  __builtin_amdgcn_global_load_lds(                                           \
      (const __attribute__((address_space(1))) void*)(g),                     \
      (__attribute__((address_space(3))) void*)(l), 16, 0, 0)

// ---------------------------------------------------------------- GN stats
__global__ __launch_bounds__(256) void gn_stats_k(const float* __restrict__ x,
                                                  float2* __restrict__ stats) {
  int bg = blockIdx.x;            // b*32+g
  int b = bg >> 5, g = bg & 31;
  int tid = threadIdx.x;
  int c = tid & 15, s0 = tid >> 4;
  const float* base = x + (long)b * SP * NC + g * 16 + c;
  float s = 0.f, ss = 0.f;
  for (int sp = s0; sp < SP; sp += 16) {
    float v = base[(long)sp * NC];
    s += v; ss += v * v;
  }
  for (int o = 32; o > 0; o >>= 1) { s += __shfl_xor(s, o); ss += __shfl_xor(ss, o); }
  __shared__ float rs[4], rss[4];
  int lane = tid & 63, wv = tid >> 6;
  if (lane == 0) { rs[wv] = s; rss[wv] = ss; }
  __syncthreads();
  if (tid == 0) {
    float S = rs[0] + rs[1] + rs[2] + rs[3];
    float SS = rss[0] + rss[1] + rss[2] + rss[3];
    float mean = S * (1.f / 16384.f);
    float var  = SS * (1.f / 16384.f) - mean * mean;
    stats[bg] = make_float2(mean, rsqrtf(var + EPSV));
  }
}

// ---------------------------------------------------------------- GN apply -> xn bf16
__global__ __launch_bounds__(256) void gn_apply_k(const float* __restrict__ x,
                                                  const float2* __restrict__ stats,
                                                  const float* __restrict__ gamma,
                                                  const float* __restrict__ beta,
                                                  unsigned short* __restrict__ xn) {
  long t = (long)blockIdx.x * 256 + threadIdx.x;
  long base = t * 8;
  int c = (int)(base & 511);
  int b = (int)(base >> 19);
  float2 st = stats[b * NG + (c >> 4)];
  f32x4 v0 = *reinterpret_cast<const f32x4*>(x + base);
  f32x4 v1 = *reinterpret_cast<const f32x4*>(x + base + 4);
  f32x4 g0 = *reinterpret_cast<const f32x4*>(gamma + c);
  f32x4 g1 = *reinterpret_cast<const f32x4*>(gamma + c + 4);
  f32x4 b0 = *reinterpret_cast<const f32x4*>(beta + c);
  f32x4 b1 = *reinterpret_cast<const f32x4*>(beta + c + 4);
  short8 o;
  #pragma unroll
  for (int q = 0; q < 4; ++q) {
    float sc = st.y * g0[q];
    o[q] = (short)f2bf(v0[q] * sc + (b0[q] - st.x * sc));
  }
  #pragma unroll
  for (int q = 0; q < 4; ++q) {
    float sc = st.y * g1[q];
    o[q + 4] = (short)f2bf(v1[q] * sc + (b1[q] - st.x * sc));
  }
  *reinterpret_cast<short8*>(xn + base) = o;
}

// ---------------------------------------------------------------- weight packing
__global__ __launch_bounds__(256) void pack_wqkv_k(const float* __restrict__ W,
                                                   const float* __restrict__ bq,
                                                   unsigned short* __restrict__ Wp,
                                                   float* __restrict__ bp) {
  int idx = blockIdx.x * 256 + threadIdx.x;     // 786432
  int n = idx >> 9, c = idx & 511;
  int e = n >> 9, a = n & 511;
  Wp[idx] = f2bf(W[((long)c * 512 + a) * 3 + e]);
  if (idx < 1536) {
    int e2 = idx >> 9, a2 = idx & 511;
    bp[idx] = bq[a2 * 3 + e2];
  }
}

__global__ __launch_bounds__(256) void pack_wout_k(const float* __restrict__ W,
                                                   unsigned short* __restrict__ Wp) {
  int idx = blockIdx.x * 256 + threadIdx.x;     // 262144
  int n = idx >> 9, c = idx & 511;
  Wp[idx] = f2bf(W[(long)c * 512 + n]);
}

// ---------------------------------------------------------------- V transpose
__global__ void transpose_v_k(const unsigned short* __restrict__ qkv,
                              unsigned short* __restrict__ vT) {
  __shared__ unsigned short t[32][33];
  int bs = blockIdx.x, bc = blockIdx.y, b = blockIdx.z;
  int tx = threadIdx.x, ty = threadIdx.y;     // 32 x 8
  #pragma unroll
  for (int k = 0; k < 4; ++k) {
    int s = bs * 32 + ty + k * 8, c = bc * 32 + tx;
    t[ty + k * 8][tx] = qkv[((long)b * SP + s) * 1536 + 1024 + c];
  }
  __syncthreads();
  #pragma unroll
  for (int k = 0; k < 4; ++k) {
    int c = bc * 32 + ty + k * 8, s = bs * 32 + tx;
    vT[((long)b * NC + c) * SP + s] = t[tx][ty + k * 8];
  }
}

// ---------------------------------------------------------------- softmax (bf16 in-place)
__global__ __launch_bounds__(256) void softmax_k(unsigned short* __restrict__ S) {
  long row = blockIdx.x;
  unsigned short* r = S + row * 1024;
  int tid = threadIdx.x, lane = tid & 63, wv = tid >> 6;
  short4v raw = *reinterpret_cast<const short4v*>(r + tid * 4);
  float v[4];
  #pragma unroll
  for (int q = 0; q < 4; ++q) v[q] = bf2f((unsigned short)raw[q]);
  float m = fmaxf(fmaxf(v[0], v[1]), fmaxf(v[2], v[3]));
  for (int o = 32; o > 0; o >>= 1) m = fmaxf(m, __shfl_xor(m, o));
  __shared__ float wm[4], ws[4];
  if (lane == 0) wm[wv] = m;
  __syncthreads();
  float rmax = fmaxf(fmaxf(wm[0], wm[1]), fmaxf(wm[2], wm[3]));
  float e[4]; float ssum = 0.f;
  #pragma unroll
  for (int q = 0; q < 4; ++q) { e[q] = __expf(v[q] - rmax); ssum += e[q]; }
  for (int o = 32; o > 0; o >>= 1) ssum += __shfl_xor(ssum, o);
  if (lane == 0) ws[wv] = ssum;
  __syncthreads();
  float inv = 1.f / (ws[0] + ws[1] + ws[2] + ws[3]);
  short4v pv;
  #pragma unroll
  for (int q = 0; q < 4; ++q) pv[q] = (short)f2bf(e[q] * inv);
  *reinterpret_cast<short4v*>(r + tid * 4) = pv;
}

// ================================================================ 256x256 GEMM
// C[m][n]=sum_k A[m][k]*B'[n][k], bf16. Tile 256x256, BK=32, 8 waves (2M x 4N),
// per-wave 128x64 output (a[8] x b[4] frags, 32 MFMA/K-tile). Ring-4 LDS K-tile
// slots (A 16KB + B 16KB = 32KB/slot, 128KB total). Stage 3 ahead, 4 gload/thr
// per tile, counted vmcnt(4) steady / vmcnt(0) tail. One s_barrier per K-tile.
// Fragment dbuf across K-tiles (sets 0/1). Swizzle identical to the verified
// r8 involution: slot8' = ((r&1)*4+s) ^ ((r>>1)&7) in 128B super-rows.
// Ledger: entering iter t outstanding={t+2}(4 ops); stage(t+3)->8; end vmcnt(4)
// retires t+2 (read next iter). WAR: stage slot (t-1)&3, reads drained >=2
// barriers earlier. EPI: 0 = bf16 out + f32 bias, 2 = bf16 out * scale.
template <int EPI>
__global__ __launch_bounds__(512, 2) void gemm256(
    const unsigned short* __restrict__ Ap, long strideA, int lda,
    const unsigned short* __restrict__ Bp, long strideB, int ldb,
    unsigned short* __restrict__ Op, long strideO, int ldo,
    const float* __restrict__ bias, int K, float scale) {
  constexpr int SLOT = 32768;              // A 16KB + B 16KB
  extern __shared__ unsigned char smem[];  // 4 * 32768 = 131072
  const int tid = threadIdx.x;
  const int lane = tid & 63, wv = tid >> 6;
  const int wm2 = wv >> 2, wn4 = wv & 3;

  // bijective XCD swizzle (requires nwg % 8 == 0)
  const int nwg  = gridDim.x * gridDim.y;
  const int flat = blockIdx.y * gridDim.x + blockIdx.x;
  const int w    = (flat & 7) * (nwg >> 3) + (flat >> 3);
  const int bn = (w % gridDim.x) * 256;
  const int bm = (w / gridDim.x) * 256;
  const int z = blockIdx.z;
  const unsigned short* Ag = Ap + (long)z * strideA;
  const unsigned short* Bg = Bp + (long)z * strideB;

  // ---- stage-source offsets (inverse-swizzled global; LDS dest linear)
  long offA0, offA1, offB0, offB1;
  { int sid = tid, sr = sid >> 3, sl = (sid & 7) ^ (sr & 7);
    offA0 = (long)(bm + sr * 2 + (sl >> 2)) * lda + (sl & 3) * 8;
    offB0 = (long)(bn + sr * 2 + (sl >> 2)) * ldb + (sl & 3) * 8;
    sid = 512 + tid; sr = sid >> 3; sl = (sid & 7) ^ (sr & 7);
    offA1 = (long)(bm + sr * 2 + (sl >> 2)) * lda + (sl & 3) * 8;
    offB1 = (long)(bn + sr * 2 + (sl >> 2)) * ldb + (sl & 3) * 8; }
  const int ldsA0 = wv * 1024;
  const int ldsA1 = 8192  + wv * 1024;
  const int ldsB0 = 16384 + wv * 1024;
  const int ldsB1 = 24576 + wv * 1024;

  // ---- swizzled LDS read offsets: A frags i=0..7, B frags j=0..3
  int aoff[8], boff[4];
  #pragma unroll
  for (int i = 0; i < 8; ++i) {
    int r = wm2 * 128 + i * 16 + (lane & 15);
    int sr = r >> 1, sl = ((r & 1) * 4 + (lane >> 4)) ^ (sr & 7);
    aoff[i] = sr * 128 + sl * 16;
  }
  #pragma unroll
  for (int j = 0; j < 4; ++j) {
    int r = wn4 * 64 + j * 16 + (lane & 15);
    int sr = r >> 1, sl = ((r & 1) * 4 + (lane >> 4)) ^ (sr & 7);
    boff[j] = 16384 + sr * 128 + sl * 16;
  }

#define STAGE6(tt, sb) do { long kt = (long)(tt) * 32;                \
    GLOAD_LDS16(Ag + offA0 + kt, smem + (sb) + ldsA0);                \
    GLOAD_LDS16(Ag + offA1 + kt, smem + (sb) + ldsA1);                \
    GLOAD_LDS16(Bg + offB0 + kt, smem + (sb) + ldsB0);                \
    GLOAD_LDS16(Bg + offB1 + kt, smem + (sb) + ldsB1); } while (0)

#define READS6(av, bv, sa) do {                                       \
    _Pragma("unroll")                                                 \
    for (int i = 0; i < 8; ++i)                                       \
      av[i] = *reinterpret_cast<const short8*>((sa) + aoff[i]);       \
    _Pragma("unroll")                                                 \
    for (int j = 0; j < 4; ++j)                                       \
      bv[j] = *reinterpret_cast<const short8*>((sa) + boff[j]); } while (0)

#define MFMA32(av, bv) do {                                           \
    _Pragma("unroll")                                                 \
    for (int i = 0; i < 8; ++i)                                       \
      _Pragma("unroll")                                               \
      for (int j = 0; j < 4; ++j)                                     \
        acc[i][j] = __builtin_amdgcn_mfma_f32_16x16x32_bf16(          \
            __builtin_bit_cast(bf16x8v, av[i]),                       \
            __builtin_bit_cast(bf16x8v, bv[j]), acc[i][j], 0, 0, 0);  \
    } while (0)

  const int NT = K >> 5;                   // >= 16 for all our shapes
  // ---- prologue: stage tiles 0,1,2 (12 ops); vmcnt(4) lands tiles 0,1.
  #pragma unroll
  for (int t = 0; t < 3; ++t)
    STAGE6(t, t * SLOT);
  asm volatile("s_waitcnt vmcnt(4)" ::: "memory");
  __builtin_amdgcn_s_barrier();
  __builtin_amdgcn_sched_barrier(0);

  short8 a0[8], b0[4], a1[8], b1[4];
  READS6(a0, b0, smem);                    // tile 0 -> set0
  f32x4 acc[8][4] = {};

  for (int t = 0; t < NT; t += 2) {
    // even sub-iter: consume tile t (set0); read t+1 -> set1; stage t+3
    if (t + 3 < NT) STAGE6(t + 3, ((t + 3) & 3) * SLOT);
    if (t + 1 < NT) { const unsigned char* sa = smem + ((t + 1) & 3) * SLOT; READS6(a1, b1, sa); }
    __builtin_amdgcn_sched_barrier(0);
    __builtin_amdgcn_s_setprio(1);
    MFMA32(a0, b0);
    __builtin_amdgcn_s_setprio(0);
    __builtin_amdgcn_sched_barrier(0);
    if (t + 3 < NT) asm volatile("s_waitcnt vmcnt(4)" ::: "memory");
    else            asm volatile("s_waitcnt vmcnt(0)" ::: "memory");
    __builtin_amdgcn_s_barrier();
    __builtin_amdgcn_sched_barrier(0);

    // odd sub-iter: consume tile t+1 (set1); read t+2 -> set0; stage t+4
    if (t + 1 < NT) {
      if (t + 4 < NT) STAGE6(t + 4, ((t + 4) & 3) * SLOT);
      if (t + 2 < NT) { const unsigned char* sa = smem + ((t + 2) & 3) * SLOT; READS6(a0, b0, sa); }
      __builtin_amdgcn_sched_barrier(0);
      __builtin_amdgcn_s_setprio(1);
      MFMA32(a1, b1);
      __builtin_amdgcn_s_setprio(0);
      __builtin_amdgcn_sched_barrier(0);
      if (t + 4 < NT) asm volatile("s_waitcnt vmcnt(4)" ::: "memory");
      else            asm volatile("s_waitcnt vmcnt(0)" ::: "memory");
      __builtin_amdgcn_s_barrier();
      __builtin_amdgcn_sched_barrier(0);
    }
  }
#undef STAGE6
#undef READS6
#undef MFMA32

  // ---- epilogue  (C/D map: col=lane&15, row=(lane>>4)*4+reg  [m89])
  const int colb = bn + wn4 * 64 + (lane & 15);
  const int rowb = bm + wm2 * 128 + (lane >> 4) * 4;
  #pragma unroll
  for (int i = 0; i < 8; ++i) {
    #pragma unroll
    for (int r = 0; r < 4; ++r) {
      long rowg = rowb + i * 16 + r;
      #pragma unroll
      for (int j = 0; j < 4; ++j) {
        int colg = colb + j * 16;
        float v = acc[i][j][r];
        if (EPI == 0) {
          v += bias[colg];
          Op[(long)z * strideO + rowg * ldo + colg] = f2bf(v);
        } else {
          Op[(long)z * strideO + rowg * ldo + colg] = f2bf(v * scale);
        }
      }
    }
  }
}

// ================================================================ 128x256 GEMM (r10, proven)
// EPI: 2 = bf16 out * scale, 3 = fp32 out + bias + residual
template <int EPI>
__global__ __launch_bounds__(512, 2) void gemm8(
    const unsigned short* __restrict__ Ap, long strideA, int lda,
    const unsigned short* __restrict__ Bp, long strideB, int ldb,
    void* __restrict__ Op, long strideO, int ldo,
    const float* __restrict__ bias, const float* __restrict__ residual,
    int K, float scale) {
  constexpr int SLOT = 24576;              // A 8KB + B 16KB per K-tile
  extern __shared__ unsigned char smem[];  // 4 * 24576 = 98304
  const int tid = threadIdx.x;
  const int lane = tid & 63, wv = tid >> 6;
  const int wm2 = wv >> 2, wn4 = wv & 3;

  const int nwg  = gridDim.x * gridDim.y;
  const int flat = blockIdx.y * gridDim.x + blockIdx.x;
  const int w    = (flat & 7) * (nwg >> 3) + (flat >> 3);
  const int bn = (w % gridDim.x) * 256;
  const int bm = (w / gridDim.x) * 128;
  const int z = blockIdx.z;
  const unsigned short* Ag = Ap + (long)z * strideA;
  const unsigned short* Bg = Bp + (long)z * strideB;

  long offA;
  { int sid = tid, sr = sid >> 3, sl = (sid & 7) ^ (sr & 7);
    offA = (long)(bm + sr * 2 + (sl >> 2)) * lda + (sl & 3) * 8; }
  long offB0, offB1;
  { int sid = tid, sr = sid >> 3, sl = (sid & 7) ^ (sr & 7);
    offB0 = (long)(bn + sr * 2 + (sl >> 2)) * ldb + (sl & 3) * 8;
    sid = 512 + tid; sr = sid >> 3; sl = (sid & 7) ^ (sr & 7);
    offB1 = (long)(bn + sr * 2 + (sl >> 2)) * ldb + (sl & 3) * 8; }
  const int ldsA_off  = wv * 1024;
  const int ldsB0_off = 8192 + wv * 1024;
  const int ldsB1_off = 16384 + wv * 1024;

  int aoff[4], boff[4];
  #pragma unroll
  for (int i = 0; i < 4; ++i) {
    int r = wm2 * 64 + i * 16 + (lane & 15);
    int sr = r >> 1, sl = ((r & 1) * 4 + (lane >> 4)) ^ (sr & 7);
    aoff[i] = sr * 128 + sl * 16;
  }
  #pragma unroll
  for (int j = 0; j < 4; ++j) {
    int r = wn4 * 64 + j * 16 + (lane & 15);
    int sr = r >> 1, sl = ((r & 1) * 4 + (lane >> 4)) ^ (sr & 7);
    boff[j] = 8192 + sr * 128 + sl * 16;
  }

#define STAGE(tt, sb) do { long kt = (long)(tt) * 32;                 \
    GLOAD_LDS16(Ag + offA + kt,  smem + (sb) + ldsA_off);             \
    GLOAD_LDS16(Bg + offB0 + kt, smem + (sb) + ldsB0_off);            \
    GLOAD_LDS16(Bg + offB1 + kt, smem + (sb) + ldsB1_off); } while (0)

#define READS(av, bv, sa) do {                                        \
    _Pragma("unroll")                                                 \
    for (int i = 0; i < 4; ++i)                                       \
      av[i] = *reinterpret_cast<const short8*>((sa) + aoff[i]);       \
    _Pragma("unroll")                                                 \
    for (int j = 0; j < 4; ++j)                                       \
      bv[j] = *reinterpret_cast<const short8*>((sa) + boff[j]); } while (0)

#define MFMA16(av, bv) do {                                           \
    _Pragma("unroll")                                                 \
    for (int i = 0; i < 4; ++i)                                       \
      _Pragma("unroll")                                               \
      for (int j = 0; j < 4; ++j)                                     \
        acc[i][j] = __builtin_amdgcn_mfma_f32_16x16x32_bf16(          \
            __builtin_bit_cast(bf16x8v, av[i]),                       \
            __builtin_bit_cast(bf16x8v, bv[j]), acc[i][j], 0, 0, 0);  \
    } while (0)

  const int NT = K >> 5;
  #pragma unroll
  for (int t = 0; t < 3; ++t)
    if (t < NT) STAGE(t, t * SLOT);
  asm volatile("s_waitcnt vmcnt(3)" ::: "memory");
  __builtin_amdgcn_s_barrier();
  __builtin_amdgcn_sched_barrier(0);

  short8 a0[4], b0[4], a1[4], b1[4];
  READS(a0, b0, smem);
  f32x4 acc[4][4] = {};

  for (int t = 0; t < NT; t += 2) {
    if (t + 3 < NT) STAGE(t + 3, ((t + 3) & 3) * SLOT);
    if (t + 1 < NT) { const unsigned char* sa = smem + ((t + 1) & 3) * SLOT; READS(a1, b1, sa); }
    __builtin_amdgcn_sched_barrier(0);
    __builtin_amdgcn_s_setprio(1);
    MFMA16(a0, b0);
    __builtin_amdgcn_s_setprio(0);
    __builtin_amdgcn_sched_barrier(0);
    if (t + 3 < NT) asm volatile("s_waitcnt vmcnt(3)" ::: "memory");
    else            asm volatile("s_waitcnt vmcnt(0)" ::: "memory");
    __builtin_amdgcn_s_barrier();
    __builtin_amdgcn_sched_barrier(0);

    if (t + 1 < NT) {
      if (t + 4 < NT) STAGE(t + 4, ((t + 4) & 3) * SLOT);
      if (t + 2 < NT) { const unsigned char* sa = smem + ((t + 2) & 3) * SLOT; READS(a0, b0, sa); }
      __builtin_amdgcn_sched_barrier(0);
      __builtin_amdgcn_s_setprio(1);
      MFMA16(a1, b1);
      __builtin_amdgcn_s_setprio(0);
      __builtin_amdgcn_sched_barrier(0);
      if (t + 4 < NT) asm volatile("s_waitcnt vmcnt(3)" ::: "memory");
      else            asm volatile("s_waitcnt vmcnt(0)" ::: "memory");
      __builtin_amdgcn_s_barrier();
      __builtin_amdgcn_sched_barrier(0);
    }
  }
#undef STAGE
#undef READS
#undef MFMA16

  const int colb = bn + wn4 * 64 + (lane & 15);
  const int rowb = bm + wm2 * 64 + (lane >> 4) * 4;
  #pragma unroll
  for (int i = 0; i < 4; ++i) {
    #pragma unroll
    for (int r = 0; r < 4; ++r) {
      int rowg = rowb + i * 16 + r;
      #pragma unroll
      for (int j = 0; j < 4; ++j) {
        int colg = colb + j * 16;
        float v = acc[i][j][r];
        if (EPI == 2) {
          ((unsigned short*)Op)[(long)z * strideO + (long)rowg * ldo + colg] = f2bf(v * scale);
        } else {
          v += bias[colg] + residual[(long)rowg * ldo + colg];
          ((float*)Op)[(long)rowg * ldo + colg] = v;
        }
      }
    }
  }
}

// ---------------------------------------------------------------- launch
extern "C" void kernel_launch(void* const* d_in, const int* in_sizes, int n_in,
                              void* d_out, int out_size, void* d_ws, size_t ws_size,
                              hipStream_t stream) {
  const float* x     = (const float*)d_in[0];
  const float* gamma = (const float*)d_in[1];
  const float* beta  = (const float*)d_in[2];
  const float* Wqkv  = (const float*)d_in[3];
  const float* bqkv  = (const float*)d_in[4];
  const float* Wout  = (const float*)d_in[5];
  const float* bout  = (const float*)d_in[6];
  float* out = (float*)d_out;

  char* ws = (char*)d_ws;
  float2*         stats = (float2*)(ws + 0);                    //   4 KB
  unsigned short* wqkvP = (unsigned short*)(ws + 4096);         // 1.5 MB
  float*          bqP   = (float*)(ws + 1576960);               //   6 KB
  unsigned short* woutT = (unsigned short*)(ws + 1583104);      // 0.5 MB
  unsigned short* qkv   = (unsigned short*)(ws + 2107392);      //  48 MB  [16384][1536] bf16
  unsigned short* vT    = (unsigned short*)(ws + 52439040);     //  16 MB  [16][512][1024] bf16
  unsigned short* Sbuf  = (unsigned short*)(ws + 69216256);     //  32 MB  [16][1024][1024] bf16 (P in-place)
  unsigned short* attn  = (unsigned short*)(ws + 136325120);    //  16 MB  [16384][512] bf16
  unsigned short* xn    = (unsigned short*)(ws + 153102336);    //  16 MB  [16384][512] bf16

  // opt in to big dynamic LDS (host-side, capture-safe)
  (void)hipFuncSetAttribute((const void*)gemm256<0>,
        hipFuncAttributeMaxDynamicSharedMemorySize, 131072);
  (void)hipFuncSetAttribute((const void*)gemm256<2>,
        hipFuncAttributeMaxDynamicSharedMemorySize, 131072);
  (void)hipFuncSetAttribute((const void*)gemm8<2>,
        hipFuncAttributeMaxDynamicSharedMemorySize, 98304);
  (void)hipFuncSetAttribute((const void*)gemm8<3>,
        hipFuncAttributeMaxDynamicSharedMemorySize, 98304);

  gn_stats_k<<<512, 256, 0, stream>>>(x, stats);
  gn_apply_k<<<4096, 256, 0, stream>>>(x, stats, gamma, beta, xn);
  pack_wqkv_k<<<3072, 256, 0, stream>>>(Wqkv, bqkv, wqkvP, bqP);
  pack_wout_k<<<1024, 256, 0, stream>>>(Wout, woutT);

  // QKV projection: xn [16384,512] x wqkvP [1536,512]^T -> qkv bf16 [16384][1536]
  gemm256<0><<<dim3(6, 64, 1), 512, 131072, stream>>>(
      xn, 0L, NC, wqkvP, 0L, NC, qkv, 0L, 1536,
      bqP, NC, 1.f);

  transpose_v_k<<<dim3(32, 16, 16), dim3(32, 8), 0, stream>>>(qkv, vT);

  // S = Q K^T * scale (bf16 out, per batch): A=q (cols 0..511), B'=k (cols 512..1023)
  gemm256<2><<<dim3(4, 4, 16), 512, 131072, stream>>>(
      qkv, (long)SP * 1536, 1536, qkv + 512, (long)SP * 1536, 1536,
      Sbuf, (long)SP * SP, SP, nullptr, NC, SCALE);

  softmax_k<<<MTOT, 256, 0, stream>>>(Sbuf);

  // attn_out = P V  (per batch): A=P bf16 [1024][1024], B'=vT [512][1024]
  gemm8<2><<<dim3(2, 8, 16), 512, 98304, stream>>>(
      Sbuf, (long)SP * SP, SP, vT, (long)NC * SP, SP,
      attn, (long)SP * NC, NC, nullptr, nullptr, SP, 1.f);

  // out = attn_out W_out + b_out + inputs
  gemm8<3><<<dim3(2, 128, 1), 512, 98304, stream>>>(
      attn, 0L, NC, woutT, 0L, NC, out, 0L, NC,
      bout, x, NC, 1.f);
}

// Round 12
// 270.649 us; speedup vs baseline: 1.0356x; 1.0088x over previous
//
#include <hip/hip_runtime.h>
#include <hip/hip_bf16.h>

// Problem constants
#define NB    16          // batch
#define SP    1024        // H*W spatial
#define NC    512         // channels
#define NG    32          // groups
#define MTOT  (NB*SP)     // 16384
#define EPSV  1e-3f
#define SCALE 0.04419417382415922f  // 512^-0.5

using f32x4   = __attribute__((ext_vector_type(4))) float;
using short8  = __attribute__((ext_vector_type(8))) short;
using short4v = __attribute__((ext_vector_type(4))) short;
using bf16x8v = __attribute__((ext_vector_type(8))) __bf16;

__device__ __forceinline__ unsigned short f2bf(float f) {
  union { float f; unsigned int u; } x; x.f = f;
  unsigned int u = x.u;
  unsigned int r = (u + 0x7FFFu + ((u >> 16) & 1u)) >> 16;  // RNE
  return (unsigned short)r;
}
__device__ __forceinline__ float bf2f(unsigned short b) {
  union { unsigned int u; float f; } x; x.u = ((unsigned int)b) << 16;
  return x.f;
}

// async 16B global->LDS (gfx950). LDS dest = wave-uniform base + lane*16.
#define GLOAD_LDS16(g, l)                                                     \
  __builtin_amdgcn_global_load_lds(                                           \
      (const __attribute__((address_space(1))) void*)(g),                     \
      (__attribute__((address_space(3))) void*)(l), 16, 0, 0)

// ---------------------------------------------------------------- GN stats
__global__ __launch_bounds__(256) void gn_stats_k(const float* __restrict__ x,
                                                  float2* __restrict__ stats) {
  int bg = blockIdx.x;            // b*32+g
  int b = bg >> 5, g = bg & 31;
  int tid = threadIdx.x;
  int c = tid & 15, s0 = tid >> 4;
  const float* base = x + (long)b * SP * NC + g * 16 + c;
  float s = 0.f, ss = 0.f;
  for (int sp = s0; sp < SP; sp += 16) {
    float v = base[(long)sp * NC];
    s += v; ss += v * v;
  }
  for (int o = 32; o > 0; o >>= 1) { s += __shfl_xor(s, o); ss += __shfl_xor(ss, o); }
  __shared__ float rs[4], rss[4];
  int lane = tid & 63, wv = tid >> 6;
  if (lane == 0) { rs[wv] = s; rss[wv] = ss; }
  __syncthreads();
  if (tid == 0) {
    float S = rs[0] + rs[1] + rs[2] + rs[3];
    float SS = rss[0] + rss[1] + rss[2] + rss[3];
    float mean = S * (1.f / 16384.f);
    float var  = SS * (1.f / 16384.f) - mean * mean;
    stats[bg] = make_float2(mean, rsqrtf(var + EPSV));
  }
}

// ---------------------------------------------------------------- GN apply -> xn bf16
__global__ __launch_bounds__(256) void gn_apply_k(const float* __restrict__ x,
                                                  const float2* __restrict__ stats,
                                                  const float* __restrict__ gamma,
                                                  const float* __restrict__ beta,
                                                  unsigned short* __restrict__ xn) {
  long t = (long)blockIdx.x * 256 + threadIdx.x;
  long base = t * 8;
  int c = (int)(base & 511);
  int b = (int)(base >> 19);
  float2 st = stats[b * NG + (c >> 4)];
  f32x4 v0 = *reinterpret_cast<const f32x4*>(x + base);
  f32x4 v1 = *reinterpret_cast<const f32x4*>(x + base + 4);
  f32x4 g0 = *reinterpret_cast<const f32x4*>(gamma + c);
  f32x4 g1 = *reinterpret_cast<const f32x4*>(gamma + c + 4);
  f32x4 b0 = *reinterpret_cast<const f32x4*>(beta + c);
  f32x4 b1 = *reinterpret_cast<const f32x4*>(beta + c + 4);
  short8 o;
  #pragma unroll
  for (int q = 0; q < 4; ++q) {
    float sc = st.y * g0[q];
    o[q] = (short)f2bf(v0[q] * sc + (b0[q] - st.x * sc));
  }
  #pragma unroll
  for (int q = 0; q < 4; ++q) {
    float sc = st.y * g1[q];
    o[q + 4] = (short)f2bf(v1[q] * sc + (b1[q] - st.x * sc));
  }
  *reinterpret_cast<short8*>(xn + base) = o;
}

// ---------------------------------------------------------------- weight packing
__global__ __launch_bounds__(256) void pack_wqkv_k(const float* __restrict__ W,
                                                   const float* __restrict__ bq,
                                                   unsigned short* __restrict__ Wp,
                                                   float* __restrict__ bp) {
  int idx = blockIdx.x * 256 + threadIdx.x;     // 786432
  int n = idx >> 9, c = idx & 511;
  int e = n >> 9, a = n & 511;
  Wp[idx] = f2bf(W[((long)c * 512 + a) * 3 + e]);
  if (idx < 1536) {
    int e2 = idx >> 9, a2 = idx & 511;
    bp[idx] = bq[a2 * 3 + e2];
  }
}

__global__ __launch_bounds__(256) void pack_wout_k(const float* __restrict__ W,
                                                   unsigned short* __restrict__ Wp) {
  int idx = blockIdx.x * 256 + threadIdx.x;     // 262144
  int n = idx >> 9, c = idx & 511;
  Wp[idx] = f2bf(W[(long)c * 512 + n]);
}

// ---------------------------------------------------------------- V transpose
__global__ void transpose_v_k(const unsigned short* __restrict__ qkv,
                              unsigned short* __restrict__ vT) {
  __shared__ unsigned short t[32][33];
  int bs = blockIdx.x, bc = blockIdx.y, b = blockIdx.z;
  int tx = threadIdx.x, ty = threadIdx.y;     // 32 x 8
  #pragma unroll
  for (int k = 0; k < 4; ++k) {
    int s = bs * 32 + ty + k * 8, c = bc * 32 + tx;
    t[ty + k * 8][tx] = qkv[((long)b * SP + s) * 1536 + 1024 + c];
  }
  __syncthreads();
  #pragma unroll
  for (int k = 0; k < 4; ++k) {
    int c = bc * 32 + ty + k * 8, s = bs * 32 + tx;
    vT[((long)b * NC + c) * SP + s] = t[tx][ty + k * 8];
  }
}

// ---------------------------------------------------------------- softmax (bf16 in-place)
__global__ __launch_bounds__(256) void softmax_k(unsigned short* __restrict__ S) {
  long row = blockIdx.x;
  unsigned short* r = S + row * 1024;
  int tid = threadIdx.x, lane = tid & 63, wv = tid >> 6;
  short4v raw = *reinterpret_cast<const short4v*>(r + tid * 4);
  float v[4];
  #pragma unroll
  for (int q = 0; q < 4; ++q) v[q] = bf2f((unsigned short)raw[q]);
  float m = fmaxf(fmaxf(v[0], v[1]), fmaxf(v[2], v[3]));
  for (int o = 32; o > 0; o >>= 1) m = fmaxf(m, __shfl_xor(m, o));
  __shared__ float wm[4], ws[4];
  if (lane == 0) wm[wv] = m;
  __syncthreads();
  float rmax = fmaxf(fmaxf(wm[0], wm[1]), fmaxf(wm[2], wm[3]));
  float e[4]; float ssum = 0.f;
  #pragma unroll
  for (int q = 0; q < 4; ++q) { e[q] = __expf(v[q] - rmax); ssum += e[q]; }
  for (int o = 32; o > 0; o >>= 1) ssum += __shfl_xor(ssum, o);
  if (lane == 0) ws[wv] = ssum;
  __syncthreads();
  float inv = 1.f / (ws[0] + ws[1] + ws[2] + ws[3]);
  short4v pv;
  #pragma unroll
  for (int q = 0; q < 4; ++q) pv[q] = (short)f2bf(e[q] * inv);
  *reinterpret_cast<short4v*>(r + tid * 4) = pv;
}

// ================================================================ 256x256 GEMM, 4-phase/K-tile
// C[m][n]=sum_k A[m][k]*B'[n][k], bf16. Tile 256x256, BK=32, 8 waves (2M x 4N),
// per-wave 128x64 output. Ring-4 K-tile slots (32KB each, 128KB LDS), stage
// lookahead 2 tiles, counted vmcnt(4) once per K-tile (vmcnt(0) only at NT-2).
// NEW (r12, m201-style): each K-tile split into 4 PHASES (quadrant q):
//   { ds_read A-frags i=2q,2q+1 (+B[0..3] in q0)  ||  1 stage-load of tile t+2
//     -> s_barrier -> lgkmcnt(0) -> setprio(1) 8 MFMA setprio(0)
//     -> [q3: counted vmcnt] -> s_barrier }
// Small per-phase batches let waves drift into role-split (some on LDS pipe,
// some on matrix pipe) -- the T3/T5 mechanism; monolithic phases proved null
// (r8-r11 all ~46us, all pipes <21%).
// Ledger: entering tile t outstanding={t+1:4}; stages add {t+2:4}; end-of-tile
// vmcnt(4) retires exactly {t+1}. WAR: slot (t+2)&3 = tile t-2's slot, drained
// 2 tile-barriers earlier. Swizzle/offsets/epilogue byte-identical to r11
// (passed, conflicts=0). EPI: 0 = bf16 out + f32 bias, 2 = bf16 out * scale.
template <int EPI>
__global__ __launch_bounds__(512, 2) void gemm256p(
    const unsigned short* __restrict__ Ap, long strideA, int lda,
    const unsigned short* __restrict__ Bp, long strideB, int ldb,
    unsigned short* __restrict__ Op, long strideO, int ldo,
    const float* __restrict__ bias, int K, float scale) {
  constexpr int SLOT = 32768;              // A 16KB + B 16KB
  extern __shared__ unsigned char smem[];  // 4 * 32768 = 131072
  const int tid = threadIdx.x;
  const int lane = tid & 63, wv = tid >> 6;
  const int wm2 = wv >> 2, wn4 = wv & 3;

  // bijective XCD swizzle (requires nwg % 8 == 0)
  const int nwg  = gridDim.x * gridDim.y;
  const int flat = blockIdx.y * gridDim.x + blockIdx.x;
  const int w    = (flat & 7) * (nwg >> 3) + (flat >> 3);
  const int bn = (w % gridDim.x) * 256;
  const int bm = (w / gridDim.x) * 256;
  const int z = blockIdx.z;
  const unsigned short* Ag = Ap + (long)z * strideA;
  const unsigned short* Bg = Bp + (long)z * strideB;

  // ---- stage-source offsets (inverse-swizzled global; LDS dest linear)
  long offA0, offA1, offB0, offB1;
  { int sid = tid, sr = sid >> 3, sl = (sid & 7) ^ (sr & 7);
    offA0 = (long)(bm + sr * 2 + (sl >> 2)) * lda + (sl & 3) * 8;
    offB0 = (long)(bn + sr * 2 + (sl >> 2)) * ldb + (sl & 3) * 8;
    sid = 512 + tid; sr = sid >> 3; sl = (sid & 7) ^ (sr & 7);
    offA1 = (long)(bm + sr * 2 + (sl >> 2)) * lda + (sl & 3) * 8;
    offB1 = (long)(bn + sr * 2 + (sl >> 2)) * ldb + (sl & 3) * 8; }
  const int ldsA0 = wv * 1024;
  const int ldsA1 = 8192  + wv * 1024;
  const int ldsB0 = 16384 + wv * 1024;
  const int ldsB1 = 24576 + wv * 1024;

  // ---- swizzled LDS read offsets: A frags i=0..7, B frags j=0..3
  int aoff[8], boff[4];
  #pragma unroll
  for (int i = 0; i < 8; ++i) {
    int r = wm2 * 128 + i * 16 + (lane & 15);
    int sr = r >> 1, sl = ((r & 1) * 4 + (lane >> 4)) ^ (sr & 7);
    aoff[i] = sr * 128 + sl * 16;
  }
  #pragma unroll
  for (int j = 0; j < 4; ++j) {
    int r = wn4 * 64 + j * 16 + (lane & 15);
    int sr = r >> 1, sl = ((r & 1) * 4 + (lane >> 4)) ^ (sr & 7);
    boff[j] = 16384 + sr * 128 + sl * 16;
  }

#define STAGE4(tt, sb) do { long kt = (long)(tt) * 32;                \
    GLOAD_LDS16(Ag + offA0 + kt, smem + (sb) + ldsA0);                \
    GLOAD_LDS16(Ag + offA1 + kt, smem + (sb) + ldsA1);                \
    GLOAD_LDS16(Bg + offB0 + kt, smem + (sb) + ldsB0);                \
    GLOAD_LDS16(Bg + offB1 + kt, smem + (sb) + ldsB1); } while (0)

  const int NT = K >> 5;                   // 16 for K=512
  // ---- prologue: stage tiles 0,1 (8 loads); vmcnt(4) lands tile 0.
  STAGE4(0, 0);
  STAGE4(1, SLOT);
  asm volatile("s_waitcnt vmcnt(4)" ::: "memory");
  __builtin_amdgcn_s_barrier();

  f32x4 acc[8][4] = {};
  for (int t = 0; t < NT; ++t) {
    const unsigned char* sa = smem + (t & 3) * SLOT;
    const int t2 = t + 2;
    const bool st = (t2 < NT);
    const int sb = (t2 & 3) * SLOT;
    const long kt2 = (long)t2 * 32;
    short8 bfr[4];
    #pragma unroll
    for (int q = 0; q < 4; ++q) {
      // ---- phase q: reads (2 A-frags; +4 B-frags in q0)
      short8 av0 = *reinterpret_cast<const short8*>(sa + aoff[2 * q]);
      short8 av1 = *reinterpret_cast<const short8*>(sa + aoff[2 * q + 1]);
      if (q == 0) {
        #pragma unroll
        for (int j = 0; j < 4; ++j)
          bfr[j] = *reinterpret_cast<const short8*>(sa + boff[j]);
      }
      // ---- one stage-load of tile t+2
      if (st) {
        if (q == 0) GLOAD_LDS16(Ag + offA0 + kt2, smem + sb + ldsA0);
        if (q == 1) GLOAD_LDS16(Ag + offA1 + kt2, smem + sb + ldsA1);
        if (q == 2) GLOAD_LDS16(Bg + offB0 + kt2, smem + sb + ldsB0);
        if (q == 3) GLOAD_LDS16(Bg + offB1 + kt2, smem + sb + ldsB1);
      }
      __builtin_amdgcn_s_barrier();
      asm volatile("s_waitcnt lgkmcnt(0)" ::: "memory");
      __builtin_amdgcn_sched_barrier(0);
      __builtin_amdgcn_s_setprio(1);
      #pragma unroll
      for (int j = 0; j < 4; ++j) {
        acc[2 * q][j] = __builtin_amdgcn_mfma_f32_16x16x32_bf16(
            __builtin_bit_cast(bf16x8v, av0),
            __builtin_bit_cast(bf16x8v, bfr[j]), acc[2 * q][j], 0, 0, 0);
        acc[2 * q + 1][j] = __builtin_amdgcn_mfma_f32_16x16x32_bf16(
            __builtin_bit_cast(bf16x8v, av1),
            __builtin_bit_cast(bf16x8v, bfr[j]), acc[2 * q + 1][j], 0, 0, 0);
      }
      __builtin_amdgcn_s_setprio(0);
      __builtin_amdgcn_sched_barrier(0);
      if (q == 3) {
        if (st)              asm volatile("s_waitcnt vmcnt(4)" ::: "memory");
        else if (t + 1 < NT) asm volatile("s_waitcnt vmcnt(0)" ::: "memory");
      }
      __builtin_amdgcn_s_barrier();
    }
  }
#undef STAGE4

  // ---- epilogue  (C/D map: col=lane&15, row=(lane>>4)*4+reg  [m89])
  const int colb = bn + wn4 * 64 + (lane & 15);
  const int rowb = bm + wm2 * 128 + (lane >> 4) * 4;
  #pragma unroll
  for (int i = 0; i < 8; ++i) {
    #pragma unroll
    for (int r = 0; r < 4; ++r) {
      long rowg = rowb + i * 16 + r;
      #pragma unroll
      for (int j = 0; j < 4; ++j) {
        int colg = colb + j * 16;
        float v = acc[i][j][r];
        if (EPI == 0) {
          v += bias[colg];
          Op[(long)z * strideO + rowg * ldo + colg] = f2bf(v);
        } else {
          Op[(long)z * strideO + rowg * ldo + colg] = f2bf(v * scale);
        }
      }
    }
  }
}

// ================================================================ 128x256 GEMM (r10/r11, proven)
// EPI: 2 = bf16 out * scale, 3 = fp32 out + bias + residual
template <int EPI>
__global__ __launch_bounds__(512, 2) void gemm8(
    const unsigned short* __restrict__ Ap, long strideA, int lda,
    const unsigned short* __restrict__ Bp, long strideB, int ldb,
    void* __restrict__ Op, long strideO, int ldo,
    const float* __restrict__ bias, const float* __restrict__ residual,
    int K, float scale) {
  constexpr int SLOT = 24576;              // A 8KB + B 16KB per K-tile
  extern __shared__ unsigned char smem[];  // 4 * 24576 = 98304
  const int tid = threadIdx.x;
  const int lane = tid & 63, wv = tid >> 6;
  const int wm2 = wv >> 2, wn4 = wv & 3;

  const int nwg  = gridDim.x * gridDim.y;
  const int flat = blockIdx.y * gridDim.x + blockIdx.x;
  const int w    = (flat & 7) * (nwg >> 3) + (flat >> 3);
  const int bn = (w % gridDim.x) * 256;
  const int bm = (w / gridDim.x) * 128;
  const int z = blockIdx.z;
  const unsigned short* Ag = Ap + (long)z * strideA;
  const unsigned short* Bg = Bp + (long)z * strideB;

  long offA;
  { int sid = tid, sr = sid >> 3, sl = (sid & 7) ^ (sr & 7);
    offA = (long)(bm + sr * 2 + (sl >> 2)) * lda + (sl & 3) * 8; }
  long offB0, offB1;
  { int sid = tid, sr = sid >> 3, sl = (sid & 7) ^ (sr & 7);
    offB0 = (long)(bn + sr * 2 + (sl >> 2)) * ldb + (sl & 3) * 8;
    sid = 512 + tid; sr = sid >> 3; sl = (sid & 7) ^ (sr & 7);
    offB1 = (long)(bn + sr * 2 + (sl >> 2)) * ldb + (sl & 3) * 8; }
  const int ldsA_off  = wv * 1024;
  const int ldsB0_off = 8192 + wv * 1024;
  const int ldsB1_off = 16384 + wv * 1024;

  int aoff[4], boff[4];
  #pragma unroll
  for (int i = 0; i < 4; ++i) {
    int r = wm2 * 64 + i * 16 + (lane & 15);
    int sr = r >> 1, sl = ((r & 1) * 4 + (lane >> 4)) ^ (sr & 7);
    aoff[i] = sr * 128 + sl * 16;
  }
  #pragma unroll
  for (int j = 0; j < 4; ++j) {
    int r = wn4 * 64 + j * 16 + (lane & 15);
    int sr = r >> 1, sl = ((r & 1) * 4 + (lane >> 4)) ^ (sr & 7);
    boff[j] = 8192 + sr * 128 + sl * 16;
  }

#define STAGE(tt, sb) do { long kt = (long)(tt) * 32;                 \
    GLOAD_LDS16(Ag + offA + kt,  smem + (sb) + ldsA_off);             \
    GLOAD_LDS16(Bg + offB0 + kt, smem + (sb) + ldsB0_off);            \
    GLOAD_LDS16(Bg + offB1 + kt, smem + (sb) + ldsB1_off); } while (0)

#define READS(av, bv, sa) do {                                        \
    _Pragma("unroll")                                                 \
    for (int i = 0; i < 4; ++i)                                       \
      av[i] = *reinterpret_cast<const short8*>((sa) + aoff[i]);       \
    _Pragma("unroll")                                                 \
    for (int j = 0; j < 4; ++j)                                       \
      bv[j] = *reinterpret_cast<const short8*>((sa) + boff[j]); } while (0)

#define MFMA16(av, bv) do {                                           \
    _Pragma("unroll")                                                 \
    for (int i = 0; i < 4; ++i)                                       \
      _Pragma("unroll")                                               \
      for (int j = 0; j < 4; ++j)                                     \
        acc[i][j] = __builtin_amdgcn_mfma_f32_16x16x32_bf16(          \
            __builtin_bit_cast(bf16x8v, av[i]),                       \
            __builtin_bit_cast(bf16x8v, bv[j]), acc[i][j], 0, 0, 0);  \
    } while (0)

  const int NT = K >> 5;
  #pragma unroll
  for (int t = 0; t < 3; ++t)
    if (t < NT) STAGE(t, t * SLOT);
  asm volatile("s_waitcnt vmcnt(3)" ::: "memory");
  __builtin_amdgcn_s_barrier();
  __builtin_amdgcn_sched_barrier(0);

  short8 a0[4], b0[4], a1[4], b1[4];
  READS(a0, b0, smem);
  f32x4 acc[4][4] = {};

  for (int t = 0; t < NT; t += 2) {
    if (t + 3 < NT) STAGE(t + 3, ((t + 3) & 3) * SLOT);
    if (t + 1 < NT) { const unsigned char* sa = smem + ((t + 1) & 3) * SLOT; READS(a1, b1, sa); }
    __builtin_amdgcn_sched_barrier(0);
    __builtin_amdgcn_s_setprio(1);
    MFMA16(a0, b0);
    __builtin_amdgcn_s_setprio(0);
    __builtin_amdgcn_sched_barrier(0);
    if (t + 3 < NT) asm volatile("s_waitcnt vmcnt(3)" ::: "memory");
    else            asm volatile("s_waitcnt vmcnt(0)" ::: "memory");
    __builtin_amdgcn_s_barrier();
    __builtin_amdgcn_sched_barrier(0);

    if (t + 1 < NT) {
      if (t + 4 < NT) STAGE(t + 4, ((t + 4) & 3) * SLOT);
      if (t + 2 < NT) { const unsigned char* sa = smem + ((t + 2) & 3) * SLOT; READS(a0, b0, sa); }
      __builtin_amdgcn_sched_barrier(0);
      __builtin_amdgcn_s_setprio(1);
      MFMA16(a1, b1);
      __builtin_amdgcn_s_setprio(0);
      __builtin_amdgcn_sched_barrier(0);
      if (t + 4 < NT) asm volatile("s_waitcnt vmcnt(3)" ::: "memory");
      else            asm volatile("s_waitcnt vmcnt(0)" ::: "memory");
      __builtin_amdgcn_s_barrier();
      __builtin_amdgcn_sched_barrier(0);
    }
  }
#undef STAGE
#undef READS
#undef MFMA16

  const int colb = bn + wn4 * 64 + (lane & 15);
  const int rowb = bm + wm2 * 64 + (lane >> 4) * 4;
  #pragma unroll
  for (int i = 0; i < 4; ++i) {
    #pragma unroll
    for (int r = 0; r < 4; ++r) {
      int rowg = rowb + i * 16 + r;
      #pragma unroll
      for (int j = 0; j < 4; ++j) {
        int colg = colb + j * 16;
        float v = acc[i][j][r];
        if (EPI == 2) {
          ((unsigned short*)Op)[(long)z * strideO + (long)rowg * ldo + colg] = f2bf(v * scale);
        } else {
          v += bias[colg] + residual[(long)rowg * ldo + colg];
          ((float*)Op)[(long)rowg * ldo + colg] = v;
        }
      }
    }
  }
}

// ---------------------------------------------------------------- launch
extern "C" void kernel_launch(void* const* d_in, const int* in_sizes, int n_in,
                              void* d_out, int out_size, void* d_ws, size_t ws_size,
                              hipStream_t stream) {
  const float* x     = (const float*)d_in[0];
  const float* gamma = (const float*)d_in[1];
  const float* beta  = (const float*)d_in[2];
  const float* Wqkv  = (const float*)d_in[3];
  const float* bqkv  = (const float*)d_in[4];
  const float* Wout  = (const float*)d_in[5];
  const float* bout  = (const float*)d_in[6];
  float* out = (float*)d_out;

  char* ws = (char*)d_ws;
  float2*         stats = (float2*)(ws + 0);                    //   4 KB
  unsigned short* wqkvP = (unsigned short*)(ws + 4096);         // 1.5 MB
  float*          bqP   = (float*)(ws + 1576960);               //   6 KB
  unsigned short* woutT = (unsigned short*)(ws + 1583104);      // 0.5 MB
  unsigned short* qkv   = (unsigned short*)(ws + 2107392);      //  48 MB  [16384][1536] bf16
  unsigned short* vT    = (unsigned short*)(ws + 52439040);     //  16 MB  [16][512][1024] bf16
  unsigned short* Sbuf  = (unsigned short*)(ws + 69216256);     //  32 MB  [16][1024][1024] bf16 (P in-place)
  unsigned short* attn  = (unsigned short*)(ws + 136325120);    //  16 MB  [16384][512] bf16
  unsigned short* xn    = (unsigned short*)(ws + 153102336);    //  16 MB  [16384][512] bf16

  // opt in to big dynamic LDS (host-side, capture-safe)
  (void)hipFuncSetAttribute((const void*)gemm256p<0>,
        hipFuncAttributeMaxDynamicSharedMemorySize, 131072);
  (void)hipFuncSetAttribute((const void*)gemm256p<2>,
        hipFuncAttributeMaxDynamicSharedMemorySize, 131072);
  (void)hipFuncSetAttribute((const void*)gemm8<2>,
        hipFuncAttributeMaxDynamicSharedMemorySize, 98304);
  (void)hipFuncSetAttribute((const void*)gemm8<3>,
        hipFuncAttributeMaxDynamicSharedMemorySize, 98304);

  gn_stats_k<<<512, 256, 0, stream>>>(x, stats);
  gn_apply_k<<<4096, 256, 0, stream>>>(x, stats, gamma, beta, xn);
  pack_wqkv_k<<<3072, 256, 0, stream>>>(Wqkv, bqkv, wqkvP, bqP);
  pack_wout_k<<<1024, 256, 0, stream>>>(Wout, woutT);

  // QKV projection: xn [16384,512] x wqkvP [1536,512]^T -> qkv bf16 [16384][1536]
  gemm256p<0><<<dim3(6, 64, 1), 512, 131072, stream>>>(
      xn, 0L, NC, wqkvP, 0L, NC, qkv, 0L, 1536,
      bqP, NC, 1.f);

  transpose_v_k<<<dim3(32, 16, 16), dim3(32, 8), 0, stream>>>(qkv, vT);

  // S = Q K^T * scale (bf16 out, per batch): A=q (cols 0..511), B'=k (cols 512..1023)
  gemm256p<2><<<dim3(4, 4, 16), 512, 131072, stream>>>(
      qkv, (long)SP * 1536, 1536, qkv + 512, (long)SP * 1536, 1536,
      Sbuf, (long)SP * SP, SP, nullptr, NC, SCALE);

  softmax_k<<<MTOT, 256, 0, stream>>>(Sbuf);

  // attn_out = P V  (per batch): A=P bf16 [1024][1024], B'=vT [512][1024]
  gemm8<2><<<dim3(2, 8, 16), 512, 98304, stream>>>(
      Sbuf, (long)SP * SP, SP, vT, (long)NC * SP, SP,
      attn, (long)SP * NC, NC, nullptr, nullptr, SP, 1.f);

  // out = attn_out W_out + b_out + inputs
  gemm8<3><<<dim3(2, 128, 1), 512, 98304, stream>>>(
      attn, 0L, NC, woutT, 0L, NC, out, 0L, NC,
      bout, x, NC, 1.f);
}